// Round 1
// baseline (198.476 us; speedup 1.0000x reference)
//
#include <hip/hip_runtime.h>
#include <hip/hip_bf16.h>

typedef __attribute__((ext_vector_type(4))) short s16x4;
typedef __attribute__((ext_vector_type(4))) float f32x4;

#define GENE_N     500
#define WG_STRIDE  112          // padded gene-weight row (e>=100 zeros)
#define WSW_FRAGS  154          // 7 (L0) + 49*3 (L1..L3) A-fragments
#define WG_OFF_BYTES 81920      // gathered gene weights start here in d_ws

__device__ __forceinline__ unsigned short f2bf(float x){
  __hip_bfloat16 h = __float2bfloat16(x);
  return *reinterpret_cast<unsigned short*>(&h);
}

__device__ __forceinline__ f32x4 mfma16(s16x4 a, s16x4 b, f32x4 c){
#if __has_builtin(__builtin_amdgcn_mfma_f32_16x16x16bf16_1k)
  return __builtin_amdgcn_mfma_f32_16x16x16bf16_1k(a, b, c, 0, 0, 0);
#else
  asm volatile("v_mfma_f32_16x16x16_bf16 %0, %1, %2, %0"
               : "+v"(c) : "v"(a), "v"(b));
  return c;
#endif
}

// out[c*GENE_N+g] = bias1[gene_ix[g]]
__global__ void init_out(const int* __restrict__ gene_ix,
                         const float* __restrict__ bias1,
                         float* __restrict__ out, int n){
  int t = blockIdx.x*blockDim.x + threadIdx.x;
  if (t < n) out[t] = bias1[gene_ix[t % GENE_N]];
}

// Bake W^T (+bias slot) into per-lane A-fragment layout for 16x16x16 bf16 MFMA.
// A-frag of tile (L,m,kt): lane l, elem i -> A[u' = 16m + (l&15)][k = 16kt + (l>>4)*4 + i]
// L0: k==0 -> W0[0][u'], k==1 -> W0[1][u'], k==2 -> b0[u'], else 0
// L>=1: k<100 -> W[k][u'], k==100 -> b[u'], else 0.  u'>=100 -> 0.
__global__ void prep_weights(const float* __restrict__ W0, const float* __restrict__ b0,
                             const float* __restrict__ W1, const float* __restrict__ b1,
                             const float* __restrict__ W2, const float* __restrict__ b2,
                             const float* __restrict__ W3, const float* __restrict__ b3,
                             unsigned short* __restrict__ wsW){
  int t = blockIdx.x*blockDim.x + threadIdx.x;
  if (t >= WSW_FRAGS*64) return;
  int fr = t >> 6, lane = t & 63;
  int grp = lane >> 4, row = lane & 15;
  int L, m, kt;
  if (fr < 7){ L = 0; m = fr; kt = 0; }
  else { int r = fr - 7; L = 1 + r/49; r %= 49; m = r/7; kt = r%7; }
  int up = m*16 + row;
  const float* W = (L==0)?W0:(L==1)?W1:(L==2)?W2:W3;
  const float* B = (L==0)?b0:(L==1)?b1:(L==2)?b2:b3;
  #pragma unroll
  for (int i = 0; i < 4; ++i){
    float val = 0.f;
    if (up < 100){
      int k = kt*16 + grp*4 + i;
      if (L == 0){
        if (k < 2)        val = W[k*100 + up];
        else if (k == 2)  val = B[up];
      } else {
        if (k < 100)      val = W[k*100 + up];
        else if (k == 100) val = B[up];
      }
    }
    wsW[t*4 + i] = f2bf(val);
  }
}

// gathered gene weights, padded: wg[g][e] = weight1[gene_ix[g]][e] (e<100), else 0
__global__ void prep_wg(const int* __restrict__ gene_ix,
                        const float* __restrict__ weight1,
                        float* __restrict__ wg){
  int t = blockIdx.x*blockDim.x + threadIdx.x;
  if (t >= GENE_N*WG_STRIDE) return;
  int g = t / WG_STRIDE, e = t % WG_STRIDE;
  wg[t] = (e < 100) ? weight1[gene_ix[g]*100 + e] : 0.f;
}

#define RELUPACK(GDST, INJECT)                                         \
  _Pragma("unroll")                                                    \
  for (int m = 0; m < 7; ++m){                                         \
    float r0 = fmaxf(acc[m][0], 0.f);                                  \
    float r1 = fmaxf(acc[m][1], 0.f);                                  \
    float r2 = fmaxf(acc[m][2], 0.f);                                  \
    float r3 = fmaxf(acc[m][3], 0.f);                                  \
    if (INJECT && m == 6 && grp == 1) r0 = 1.0f;  /* u==100 bias slot */\
    GDST[m][0] = (short)f2bf(r0);                                      \
    GDST[m][1] = (short)f2bf(r1);                                      \
    GDST[m][2] = (short)f2bf(r2);                                      \
    GDST[m][3] = (short)f2bf(r3);                                      \
  }

__global__ __launch_bounds__(64, 1)
void frag_mlp_pool(const int* __restrict__ coords, const int* __restrict__ cxg,
                   const unsigned short* __restrict__ wsW,
                   const float* __restrict__ wg,
                   float* __restrict__ out, int nfrag, int ntiles){
  const int lane = threadIdx.x & 63;
  const int grp = lane >> 4, row = lane & 15;
  const s16x4* wf = (const s16x4*)wsW;

  // persistent weight fragments (~308 VGPRs)
  s16x4 A0[7], A1[49], A2[49], A3[49];
  #pragma unroll
  for (int i = 0; i < 7;  ++i) A0[i] = wf[i*64 + lane];
  #pragma unroll
  for (int i = 0; i < 49; ++i) A1[i] = wf[(7   + i)*64 + lane];
  #pragma unroll
  for (int i = 0; i < 49; ++i) A2[i] = wf[(56  + i)*64 + lane];
  #pragma unroll
  for (int i = 0; i < 49; ++i) A3[i] = wf[(105 + i)*64 + lane];

  const f32x4 zero = {0.f, 0.f, 0.f, 0.f};

  for (int tile = blockIdx.x; tile < ntiles; tile += gridDim.x){
    int fbase = tile*16;
    int f  = fbase + row;
    int fc = (f < nfrag) ? f : (nfrag - 1);

    // layer 0: B supplies {x0, x1, 1, 0} in k=0..3 (lanes>=16 hit zero A cols)
    int2 cd = ((const int2*)coords)[fc];
    s16x4 bx;
    bx[0] = (short)f2bf((float)cd.x * 1e-3f);
    bx[1] = (short)f2bf((float)cd.y * 1e-3f);
    bx[2] = (short)0x3F80;   // 1.0bf16 -> bias row
    bx[3] = 0;

    f32x4 acc[7];
    #pragma unroll
    for (int m = 0; m < 7; ++m) acc[m] = mfma16(A0[m], bx, zero);

    s16x4 g[7];
    RELUPACK(g, 1)

    // layer 1
    #pragma unroll
    for (int m = 0; m < 7; ++m){
      f32x4 a = zero;
      #pragma unroll
      for (int kt = 0; kt < 7; ++kt) a = mfma16(A1[m*7 + kt], g[kt], a);
      acc[m] = a;
    }
    RELUPACK(g, 1)

    // layer 2
    #pragma unroll
    for (int m = 0; m < 7; ++m){
      f32x4 a = zero;
      #pragma unroll
      for (int kt = 0; kt < 7; ++kt) a = mfma16(A2[m*7 + kt], g[kt], a);
      acc[m] = a;
    }
    RELUPACK(g, 1)

    // layer 3 (linear, emb stays f32 in acc)
    #pragma unroll
    for (int m = 0; m < 7; ++m){
      f32x4 a = zero;
      #pragma unroll
      for (int kt = 0; kt < 7; ++kt) a = mfma16(A3[m*7 + kt], g[kt], a);
      acc[m] = a;
    }

    // epilogue: per-fragment dot(emb, wg[gene]) and pooled atomic add
    int cxgv = cxg[fc];
    int gbin = cxgv % GENE_N;
    const float* wrow = wg + gbin*WG_STRIDE + grp*4;
    float s = 0.f;
    #pragma unroll
    for (int m = 0; m < 7; ++m){
      float4 w = *(const float4*)(wrow + m*16);
      s += acc[m][0]*w.x + acc[m][1]*w.y + acc[m][2]*w.z + acc[m][3]*w.w;
    }
    s += __shfl_xor(s, 16);
    s += __shfl_xor(s, 32);
    if (lane < 16 && f < nfrag) atomicAdd(out + cxgv, s);
  }
}

extern "C" void kernel_launch(void* const* d_in, const int* in_sizes, int n_in,
                              void* d_out, int out_size, void* d_ws, size_t ws_size,
                              hipStream_t stream){
  const int* coords  = (const int*)d_in[0];
  const int* cxg     = (const int*)d_in[1];
  const int* gene_ix = (const int*)d_in[4];
  const float* W0 = (const float*)d_in[5];
  const float* b0 = (const float*)d_in[6];
  const float* W1 = (const float*)d_in[7];
  const float* b1 = (const float*)d_in[8];
  const float* W2 = (const float*)d_in[9];
  const float* b2 = (const float*)d_in[10];
  const float* W3 = (const float*)d_in[11];
  const float* b3 = (const float*)d_in[12];
  const float* weight1 = (const float*)d_in[13];
  const float* bias1   = (const float*)d_in[14];

  int nfrag  = in_sizes[1];             // 1,000,000
  int ntiles = (nfrag + 15) / 16;

  unsigned short* wsW = (unsigned short*)d_ws;
  float* wg = (float*)((char*)d_ws + WG_OFF_BYTES);
  float* out = (float*)d_out;

  hipLaunchKernelGGL(init_out, dim3((out_size + 255)/256), dim3(256), 0, stream,
                     gene_ix, bias1, out, out_size);
  hipLaunchKernelGGL(prep_weights, dim3((WSW_FRAGS*64 + 255)/256), dim3(256), 0, stream,
                     W0, b0, W1, b1, W2, b2, W3, b3, wsW);
  hipLaunchKernelGGL(prep_wg, dim3((GENE_N*WG_STRIDE + 255)/256), dim3(256), 0, stream,
                     gene_ix, weight1, wg);
  hipLaunchKernelGGL(frag_mlp_pool, dim3(1024), dim3(64), 0, stream,
                     coords, cxg, wsW, wg, out, nfrag, ntiles);
}

// Round 5
// 180.962 us; speedup vs baseline: 1.0968x; 1.0968x over previous
//
#include <hip/hip_runtime.h>
#include <hip/hip_bf16.h>

typedef __attribute__((ext_vector_type(4))) short s16x4;
typedef __attribute__((ext_vector_type(4))) float f32x4;

#define GENE_N     500
#define WG_STRIDE  112          // padded gene-weight row (e>=100 zeros)
#define WSW_FRAGS  154          // 7 (L0) + 49*3 (L1..L3) A-fragments
#define WG_OFF_BYTES 81920      // gathered gene weights start here in d_ws

__device__ __forceinline__ unsigned short f2bf(float x){
  __hip_bfloat16 h = __float2bfloat16(x);
  return *reinterpret_cast<unsigned short*>(&h);
}

__device__ __forceinline__ f32x4 mfma16(s16x4 a, s16x4 b, f32x4 c){
#if __has_builtin(__builtin_amdgcn_mfma_f32_16x16x16bf16_1k)
  return __builtin_amdgcn_mfma_f32_16x16x16bf16_1k(a, b, c, 0, 0, 0);
#else
  asm volatile("v_mfma_f32_16x16x16_bf16 %0, %1, %2, %0"
               : "+v"(c) : "v"(a), "v"(b));
  return c;
#endif
}

// out[c*GENE_N+g] = bias1[gene_ix[g]]
__global__ void init_out(const int* __restrict__ gene_ix,
                         const float* __restrict__ bias1,
                         float* __restrict__ out, int n){
  int t = blockIdx.x*blockDim.x + threadIdx.x;
  if (t < n) out[t] = bias1[gene_ix[t % GENE_N]];
}

// Bake W^T (+bias slot) into per-lane A-fragment layout for 16x16x16 bf16 MFMA.
// A-frag of tile (L,m,kt): lane l, elem i -> A[u' = 16m + (l&15)][k = 16kt + (l>>4)*4 + i]
__global__ void prep_weights(const float* __restrict__ W0, const float* __restrict__ b0,
                             const float* __restrict__ W1, const float* __restrict__ b1,
                             const float* __restrict__ W2, const float* __restrict__ b2,
                             const float* __restrict__ W3, const float* __restrict__ b3,
                             unsigned short* __restrict__ wsW){
  int t = blockIdx.x*blockDim.x + threadIdx.x;
  if (t >= WSW_FRAGS*64) return;
  int fr = t >> 6, lane = t & 63;
  int grp = lane >> 4, row = lane & 15;
  int L, m, kt;
  if (fr < 7){ L = 0; m = fr; kt = 0; }
  else { int r = fr - 7; L = 1 + r/49; r %= 49; m = r/7; kt = r%7; }
  int up = m*16 + row;
  const float* W = (L==0)?W0:(L==1)?W1:(L==2)?W2:W3;
  const float* B = (L==0)?b0:(L==1)?b1:(L==2)?b2:b3;
  #pragma unroll
  for (int i = 0; i < 4; ++i){
    float val = 0.f;
    if (up < 100){
      int k = kt*16 + grp*4 + i;
      if (L == 0){
        if (k < 2)        val = W[k*100 + up];
        else if (k == 2)  val = B[up];
      } else {
        if (k < 100)      val = W[k*100 + up];
        else if (k == 100) val = B[up];
      }
    }
    wsW[t*4 + i] = f2bf(val);
  }
}

// gathered gene weights, padded: wg[g][e] = weight1[gene_ix[g]][e] (e<100), else 0
__global__ void prep_wg(const int* __restrict__ gene_ix,
                        const float* __restrict__ weight1,
                        float* __restrict__ wg){
  int t = blockIdx.x*blockDim.x + threadIdx.x;
  if (t >= GENE_N*WG_STRIDE) return;
  int g = t / WG_STRIDE, e = t % WG_STRIDE;
  wg[t] = (e < 100) ? weight1[gene_ix[g]*100 + e] : 0.f;
}

// ---- per-tile phase helpers (all fully unrolled, constant indices) ----

__device__ __forceinline__ void mfma_layer(const s16x4* __restrict__ A,
                                           const s16x4* __restrict__ g,
                                           f32x4* __restrict__ acc){
  const f32x4 zero = {0.f,0.f,0.f,0.f};
  #pragma unroll
  for (int m = 0; m < 7; ++m){
    f32x4 a = zero;
    #pragma unroll
    for (int kt = 0; kt < 7; ++kt) a = mfma16(A[m*7 + kt], g[kt], a);
    acc[m] = a;
  }
}

// relu + pack to bf16; inject 1.0 in u==100 slot (m==6, grp==1, elem0)
__device__ __forceinline__ void pack_relu(const f32x4* __restrict__ acc,
                                          s16x4* __restrict__ g, int grp){
  #pragma unroll
  for (int m = 0; m < 7; ++m){
    float r0 = fmaxf(acc[m][0], 0.f);
    float r1 = fmaxf(acc[m][1], 0.f);
    float r2 = fmaxf(acc[m][2], 0.f);
    float r3 = fmaxf(acc[m][3], 0.f);
    if (m == 6 && grp == 1) r0 = 1.0f;   // bias row u==100
    s16x4 v;
    v[0] = (short)f2bf(r0);
    v[1] = (short)f2bf(r1);
    v[2] = (short)f2bf(r2);
    v[3] = (short)f2bf(r3);
    g[m] = v;
  }
}

// epilogue: dot(emb, wg[gene]) + cross-group reduce + pooled atomic
__device__ __forceinline__ void epi_store(const f32x4* __restrict__ acc,
                                          const float* __restrict__ wg,
                                          int grp, int lane, int f, int nfrag,
                                          int cxgv, float* __restrict__ out){
  int gbin = cxgv % GENE_N;
  const float* wrow = wg + gbin*WG_STRIDE + grp*4;
  float s = 0.f;
  #pragma unroll
  for (int m = 0; m < 7; ++m){
    float4 w = *(const float4*)(wrow + m*16);
    s += acc[m][0]*w.x + acc[m][1]*w.y + acc[m][2]*w.z + acc[m][3]*w.w;
  }
  s += __shfl_xor(s, 16);
  s += __shfl_xor(s, 32);
  if (lane < 16 && f < nfrag) atomicAdd(out + cxgv, s);
}

__device__ __forceinline__ s16x4 build_bx(int2 cd){
  s16x4 v;
  v[0] = (short)f2bf((float)cd.x * 1e-3f);
  v[1] = (short)f2bf((float)cd.y * 1e-3f);
  v[2] = (short)0x3F80;   // 1.0 -> bias row
  v[3] = 0;
  return v;
}

__global__ __launch_bounds__(64, 1)
void frag_mlp_pool(const int* __restrict__ coords, const int* __restrict__ cxg,
                   const unsigned short* __restrict__ wsW,
                   const float* __restrict__ wg,
                   float* __restrict__ out, int nfrag, int ntiles){
  const int lane = threadIdx.x & 63;
  const int grp = lane >> 4, row = lane & 15;
  const s16x4* wf = (const s16x4*)wsW;

  // persistent weight fragments (~308 regs; A-operands can live in AGPRs)
  s16x4 A0[7], A1[49], A2[49], A3[49];
  #pragma unroll
  for (int i = 0; i < 7;  ++i) A0[i] = wf[i*64 + lane];
  #pragma unroll
  for (int i = 0; i < 49; ++i) A1[i] = wf[(7   + i)*64 + lane];
  #pragma unroll
  for (int i = 0; i < 49; ++i) A2[i] = wf[(56  + i)*64 + lane];
  #pragma unroll
  for (int i = 0; i < 49; ++i) A3[i] = wf[(105 + i)*64 + lane];

  const f32x4 zero = {0.f,0.f,0.f,0.f};
  const int npairs = (ntiles + 1) >> 1;
  const int lastf = nfrag - 1;

  // preload first pair's inputs
  int p0 = blockIdx.x;
  int fA = p0*32 + row, fB = p0*32 + 16 + row;
  int cA = (fA < nfrag) ? fA : lastf;
  int cB = (fB < nfrag) ? fB : lastf;
  int2 cdA = ((const int2*)coords)[cA];
  int2 cdB = ((const int2*)coords)[cB];
  int  xgA = cxg[cA];
  int  xgB = cxg[cB];

  for (int p = p0; p < npairs; p += gridDim.x){
    int f0 = p*32 + row, f1 = p*32 + 16 + row;
    int2 cd0 = cdA, cd1 = cdB;
    int  xg0 = xgA, xg1 = xgB;

    // prefetch next pair (clamped; harmless past end)
    int pn = p + gridDim.x;
    int fAn = pn*32 + row, fBn = pn*32 + 16 + row;
    int cAn = (fAn < nfrag) ? fAn : lastf;
    int cBn = (fBn < nfrag) ? fBn : lastf;
    cdA = ((const int2*)coords)[cAn];
    cdB = ((const int2*)coords)[cBn];
    xgA = cxg[cAn];
    xgB = cxg[cBn];

    // ---- layer 0 (both tiles) ----
    s16x4 bx0 = build_bx(cd0);
    s16x4 bx1 = build_bx(cd1);
    f32x4 acc0[7], acc1[7];
    #pragma unroll
    for (int m = 0; m < 7; ++m) acc0[m] = mfma16(A0[m], bx0, zero);
    #pragma unroll
    for (int m = 0; m < 7; ++m) acc1[m] = mfma16(A0[m], bx1, zero);

    s16x4 g0[7], g1[7];
    // ---- skewed pipeline: pack(T) overlaps MFMA of the other tile ----
    pack_relu(acc0, g0, grp);
    mfma_layer(A1, g0, acc0);   pack_relu(acc1, g1, grp);
    mfma_layer(A1, g1, acc1);   pack_relu(acc0, g0, grp);
    mfma_layer(A2, g0, acc0);   pack_relu(acc1, g1, grp);
    mfma_layer(A2, g1, acc1);   pack_relu(acc0, g0, grp);
    mfma_layer(A3, g0, acc0);   pack_relu(acc1, g1, grp);
    mfma_layer(A3, g1, acc1);

    epi_store(acc0, wg, grp, lane, f0, nfrag, xg0, out);
    epi_store(acc1, wg, grp, lane, f1, nfrag, xg1, out);
  }
}

extern "C" void kernel_launch(void* const* d_in, const int* in_sizes, int n_in,
                              void* d_out, int out_size, void* d_ws, size_t ws_size,
                              hipStream_t stream){
  const int* coords  = (const int*)d_in[0];
  const int* cxg     = (const int*)d_in[1];
  const int* gene_ix = (const int*)d_in[4];
  const float* W0 = (const float*)d_in[5];
  const float* b0 = (const float*)d_in[6];
  const float* W1 = (const float*)d_in[7];
  const float* b1 = (const float*)d_in[8];
  const float* W2 = (const float*)d_in[9];
  const float* b2 = (const float*)d_in[10];
  const float* W3 = (const float*)d_in[11];
  const float* b3 = (const float*)d_in[12];
  const float* weight1 = (const float*)d_in[13];
  const float* bias1   = (const float*)d_in[14];

  int nfrag  = in_sizes[1];             // 1,000,000
  int ntiles = (nfrag + 15) / 16;

  unsigned short* wsW = (unsigned short*)d_ws;
  float* wg = (float*)((char*)d_ws + WG_OFF_BYTES);
  float* out = (float*)d_out;

  hipLaunchKernelGGL(init_out, dim3((out_size + 255)/256), dim3(256), 0, stream,
                     gene_ix, bias1, out, out_size);
  hipLaunchKernelGGL(prep_weights, dim3((WSW_FRAGS*64 + 255)/256), dim3(256), 0, stream,
                     W0, b0, W1, b1, W2, b2, W3, b3, wsW);
  hipLaunchKernelGGL(prep_wg, dim3((GENE_N*WG_STRIDE + 255)/256), dim3(256), 0, stream,
                     gene_ix, weight1, wg);
  hipLaunchKernelGGL(frag_mlp_pool, dim3(1024), dim3(64), 0, stream,
                     coords, cxg, wsW, wg, out, nfrag, ntiles);
}

// Round 6
// 172.009 us; speedup vs baseline: 1.1539x; 1.0521x over previous
//
#include <hip/hip_runtime.h>
#include <hip/hip_bf16.h>

typedef __attribute__((ext_vector_type(4))) short s16x4;
typedef __attribute__((ext_vector_type(4))) float f32x4;
typedef __attribute__((ext_vector_type(8))) unsigned short u16x8;
typedef __attribute__((ext_vector_type(8))) __bf16 bf16x8;

#define GENE_N     500
#define WG_STRIDE  112          // padded gene-weight row (e>=100 zeros)
#define WG_OFF_BYTES 81920      // gathered gene weights start here in d_ws
// weight regions inside d_ws (bytes): A = L0 x16 frags, B = hidden x32 frags, C = hidden x16 tails
#define OFF_B_BYTES 3584        // 7 frags * 64 lanes * 4 shorts * 2B
#define OFF_C_BYTES 68096       // OFF_B + 63 frag32 * 64 * 8 * 2B
#define NFRAG_TOTAL 91          // 7 (A) + 63 (B) + 21 (C)

__device__ __forceinline__ unsigned short f2bf(float x){
  __hip_bfloat16 h = __float2bfloat16(x);
  return *reinterpret_cast<unsigned short*>(&h);
}

__device__ __forceinline__ f32x4 mfma16(s16x4 a, s16x4 b, f32x4 c){
  return __builtin_amdgcn_mfma_f32_16x16x16bf16_1k(a, b, c, 0, 0, 0);
}

__device__ __forceinline__ f32x4 mfma32(bf16x8 a, bf16x8 b, f32x4 c){
  return __builtin_amdgcn_mfma_f32_16x16x32_bf16(a, b, c, 0, 0, 0);
}

// out[c*GENE_N+g] = bias1[gene_ix[g]]
__global__ void init_out(const int* __restrict__ gene_ix,
                         const float* __restrict__ bias1,
                         float* __restrict__ out, int n){
  int t = blockIdx.x*blockDim.x + threadIdx.x;
  if (t < n) out[t] = bias1[gene_ix[t % GENE_N]];
}

// Bake W^T (+bias slot) into per-lane MFMA A-fragment layouts.
// x16 frag (region A/C): lane l elem i -> A[u'=16m+(l&15)][k = kbase + (l>>4)*4 + i]
// x32 frag (region B):   elems 0-3 -> k = 32q + (l>>4)*4+i ; elems 4-7 -> k = 32q+16+(l>>4)*4+(i-4)
__global__ void prep_weights(const float* __restrict__ W0, const float* __restrict__ b0,
                             const float* __restrict__ W1, const float* __restrict__ b1,
                             const float* __restrict__ W2, const float* __restrict__ b2,
                             const float* __restrict__ W3, const float* __restrict__ b3,
                             unsigned short* __restrict__ wsW){
  int t = blockIdx.x*blockDim.x + threadIdx.x;
  if (t >= NFRAG_TOTAL*64) return;
  int fr = t >> 6, lane = t & 63;
  int grp = lane >> 4, row = lane & 15;

  if (fr < 7){
    // region A: layer-0 x16 frag, m = fr. k: 0->W0 row0, 1->W0 row1, 2->bias
    int up = fr*16 + row;
    unsigned short* dst = wsW + (fr*64 + lane)*4;
    #pragma unroll
    for (int i = 0; i < 4; ++i){
      int k = grp*4 + i;
      float val = 0.f;
      if (up < 100){
        if (k < 2)       val = W0[k*100 + up];
        else if (k == 2) val = b0[up];
      }
      dst[i] = f2bf(val);
    }
  } else if (fr < 70){
    // region B: hidden x32 frag. fb = L*21 + m*3 + q
    int fb = fr - 7;
    int L = fb/21, m = (fb%21)/3, q = fb%3;
    const float* W = (L==0)?W1:(L==1)?W2:W3;
    const float* B = (L==0)?b1:(L==1)?b2:b3;
    int up = m*16 + row;
    unsigned short* dst = wsW + OFF_B_BYTES/2 + (fb*64 + lane)*8;
    #pragma unroll
    for (int i = 0; i < 8; ++i){
      int k = 32*q + ((i < 4) ? (grp*4 + i) : (16 + grp*4 + (i-4)));
      float val = 0.f;
      if (up < 100){
        if (k < 100)       val = W[k*100 + up];
        else if (k == 100) val = B[up];
      }
      dst[i] = f2bf(val);
    }
  } else {
    // region C: hidden x16 tail frag (k = 96..111). fc = L*7 + m
    int fc = fr - 70;
    int L = fc/7, m = fc%7;
    const float* W = (L==0)?W1:(L==1)?W2:W3;
    const float* B = (L==0)?b1:(L==1)?b2:b3;
    int up = m*16 + row;
    unsigned short* dst = wsW + OFF_C_BYTES/2 + (fc*64 + lane)*4;
    #pragma unroll
    for (int i = 0; i < 4; ++i){
      int k = 96 + grp*4 + i;
      float val = 0.f;
      if (up < 100){
        if (k < 100)       val = W[k*100 + up];
        else if (k == 100) val = B[up];
      }
      dst[i] = f2bf(val);
    }
  }
}

// gathered gene weights, padded: wg[g][e] = weight1[gene_ix[g]][e] (e<100), else 0
__global__ void prep_wg(const int* __restrict__ gene_ix,
                        const float* __restrict__ weight1,
                        float* __restrict__ wg){
  int t = blockIdx.x*blockDim.x + threadIdx.x;
  if (t >= GENE_N*WG_STRIDE) return;
  int g = t / WG_STRIDE, e = t % WG_STRIDE;
  wg[t] = (e < 100) ? weight1[gene_ix[g]*100 + e] : 0.f;
}

// ---- device helpers (fully unrolled, constant indices) ----

__device__ __forceinline__ unsigned fbits(float x){ return __builtin_bit_cast(unsigned, x); }

// relu + round-half-up bf16 pack via v_perm_b32; bias 1.0 inject at m==6/grp1/elem0
__device__ __forceinline__ void pack_relu2(const f32x4* __restrict__ acc,
                                           unsigned* __restrict__ pl,
                                           unsigned* __restrict__ ph, bool selb){
  #pragma unroll
  for (int m = 0; m < 7; ++m){
    unsigned u0 = fbits(fmaxf(acc[m][0], 0.f)) + 0x8000u;
    unsigned u1 = fbits(fmaxf(acc[m][1], 0.f)) + 0x8000u;
    unsigned u2 = fbits(fmaxf(acc[m][2], 0.f)) + 0x8000u;
    unsigned u3 = fbits(fmaxf(acc[m][3], 0.f)) + 0x8000u;
    unsigned lo = __builtin_amdgcn_perm(u1, u0, 0x07060302u);
    unsigned hi = __builtin_amdgcn_perm(u3, u2, 0x07060302u);
    if (m == 6) lo = selb ? ((lo & 0xFFFF0000u) | 0x3F80u) : lo;
    pl[m] = lo; ph[m] = hi;
  }
}

__device__ __forceinline__ bf16x8 catB(unsigned a0, unsigned a1, unsigned b0, unsigned b1){
  uint4 u; u.x = a0; u.y = a1; u.z = b0; u.w = b1;
  return __builtin_bit_cast(bf16x8, u);
}

// hidden layer: 3x x32 (k=0..95) + 1x x16 tail (k=96..111, incl bias slot)
__device__ __forceinline__ void hidden_layer(const bf16x8* __restrict__ Wd,
                                             const s16x4* __restrict__ Wt,
                                             const unsigned* __restrict__ pl,
                                             const unsigned* __restrict__ ph,
                                             f32x4* __restrict__ acc){
  const f32x4 zero = {0.f,0.f,0.f,0.f};
  bf16x8 B0 = catB(pl[0], ph[0], pl[1], ph[1]);
  bf16x8 B1 = catB(pl[2], ph[2], pl[3], ph[3]);
  bf16x8 B2 = catB(pl[4], ph[4], pl[5], ph[5]);
  uint2 t6; t6.x = pl[6]; t6.y = ph[6];
  s16x4 b6 = __builtin_bit_cast(s16x4, t6);
  #pragma unroll
  for (int m = 0; m < 7; ++m){
    f32x4 a = mfma32(Wd[3*m  ], B0, zero);
    a       = mfma32(Wd[3*m+1], B1, a);
    a       = mfma32(Wd[3*m+2], B2, a);
    a       = mfma16(Wt[m],     b6, a);
    acc[m] = a;
  }
}

// epilogue: dot(emb, wg[gene]) + cross-group reduce + pooled atomic
__device__ __forceinline__ void epi_store(const f32x4* __restrict__ acc,
                                          const float* __restrict__ wg,
                                          int grp, int lane, int f, int nfrag,
                                          int cxgv, float* __restrict__ out){
  int gbin = cxgv % GENE_N;
  const float* wrow = wg + gbin*WG_STRIDE + grp*4;
  float s = 0.f;
  #pragma unroll
  for (int m = 0; m < 7; ++m){
    float4 w = *(const float4*)(wrow + m*16);
    s += acc[m][0]*w.x + acc[m][1]*w.y + acc[m][2]*w.z + acc[m][3]*w.w;
  }
  s += __shfl_xor(s, 16);
  s += __shfl_xor(s, 32);
  if (lane < 16 && f < nfrag) atomicAdd(out + cxgv, s);
}

__device__ __forceinline__ s16x4 build_bx(int2 cd){
  s16x4 v;
  v[0] = (short)f2bf((float)cd.x * 1e-3f);
  v[1] = (short)f2bf((float)cd.y * 1e-3f);
  v[2] = (short)0x3F80;   // 1.0 -> bias row
  v[3] = 0;
  return v;
}

__global__ __launch_bounds__(64, 1)
void frag_mlp_pool(const int* __restrict__ coords, const int* __restrict__ cxg,
                   const unsigned short* __restrict__ wsW,
                   const float* __restrict__ wg,
                   float* __restrict__ out, int nfrag, int ntiles){
  const int lane = threadIdx.x & 63;
  const int grp = lane >> 4, row = lane & 15;
  const bool selb = (grp == 1);

  const s16x4* wfA = (const s16x4*)wsW;
  const u16x8* wfB = (const u16x8*)(wsW + OFF_B_BYTES/2);
  const s16x4* wfC = (const s16x4*)(wsW + OFF_C_BYTES/2);

  // persistent weight fragments (~308 regs total; A-operands may live in AGPRs)
  s16x4 A0[7];
  bf16x8 W1d[21], W2d[21], W3d[21];
  s16x4 W1t[7], W2t[7], W3t[7];
  #pragma unroll
  for (int i = 0; i < 7;  ++i) A0[i] = wfA[i*64 + lane];
  #pragma unroll
  for (int i = 0; i < 21; ++i) W1d[i] = __builtin_bit_cast(bf16x8, wfB[(i     )*64 + lane]);
  #pragma unroll
  for (int i = 0; i < 21; ++i) W2d[i] = __builtin_bit_cast(bf16x8, wfB[(21 + i)*64 + lane]);
  #pragma unroll
  for (int i = 0; i < 21; ++i) W3d[i] = __builtin_bit_cast(bf16x8, wfB[(42 + i)*64 + lane]);
  #pragma unroll
  for (int i = 0; i < 7;  ++i) W1t[i] = wfC[(i     )*64 + lane];
  #pragma unroll
  for (int i = 0; i < 7;  ++i) W2t[i] = wfC[( 7 + i)*64 + lane];
  #pragma unroll
  for (int i = 0; i < 7;  ++i) W3t[i] = wfC[(14 + i)*64 + lane];

  const f32x4 zero = {0.f,0.f,0.f,0.f};
  const int npairs = (ntiles + 1) >> 1;
  const int lastf = nfrag - 1;

  // preload first pair's inputs
  int p0 = blockIdx.x;
  int fA = p0*32 + row, fB = p0*32 + 16 + row;
  int cA = (fA < nfrag) ? fA : lastf;
  int cB = (fB < nfrag) ? fB : lastf;
  int2 cdA = ((const int2*)coords)[cA];
  int2 cdB = ((const int2*)coords)[cB];
  int  xgA = cxg[cA];
  int  xgB = cxg[cB];

  for (int p = p0; p < npairs; p += gridDim.x){
    int f0 = p*32 + row, f1 = p*32 + 16 + row;
    int2 cd0 = cdA, cd1 = cdB;
    int  xg0 = xgA, xg1 = xgB;

    // prefetch next pair (clamped; harmless past end)
    int pn = p + gridDim.x;
    int fAn = pn*32 + row, fBn = pn*32 + 16 + row;
    int cAn = (fAn < nfrag) ? fAn : lastf;
    int cBn = (fBn < nfrag) ? fBn : lastf;
    cdA = ((const int2*)coords)[cAn];
    cdB = ((const int2*)coords)[cBn];
    xgA = cxg[cAn];
    xgB = cxg[cBn];

    // ---- layer 0 (both tiles, x16) ----
    s16x4 bx0 = build_bx(cd0);
    s16x4 bx1 = build_bx(cd1);
    f32x4 acc0[7], acc1[7];
    #pragma unroll
    for (int m = 0; m < 7; ++m) acc0[m] = mfma16(A0[m], bx0, zero);
    #pragma unroll
    for (int m = 0; m < 7; ++m) acc1[m] = mfma16(A0[m], bx1, zero);

    unsigned pl0[7], ph0[7], pl1[7], ph1[7];
    // ---- skewed pipeline: pack(T) between the other tile's MFMA layers ----
    pack_relu2(acc0, pl0, ph0, selb);
    hidden_layer(W1d, W1t, pl0, ph0, acc0);   pack_relu2(acc1, pl1, ph1, selb);
    hidden_layer(W1d, W1t, pl1, ph1, acc1);   pack_relu2(acc0, pl0, ph0, selb);
    hidden_layer(W2d, W2t, pl0, ph0, acc0);   pack_relu2(acc1, pl1, ph1, selb);
    hidden_layer(W2d, W2t, pl1, ph1, acc1);   pack_relu2(acc0, pl0, ph0, selb);
    hidden_layer(W3d, W3t, pl0, ph0, acc0);   pack_relu2(acc1, pl1, ph1, selb);
    hidden_layer(W3d, W3t, pl1, ph1, acc1);

    epi_store(acc0, wg, grp, lane, f0, nfrag, xg0, out);
    epi_store(acc1, wg, grp, lane, f1, nfrag, xg1, out);
  }
}

extern "C" void kernel_launch(void* const* d_in, const int* in_sizes, int n_in,
                              void* d_out, int out_size, void* d_ws, size_t ws_size,
                              hipStream_t stream){
  const int* coords  = (const int*)d_in[0];
  const int* cxg     = (const int*)d_in[1];
  const int* gene_ix = (const int*)d_in[4];
  const float* W0 = (const float*)d_in[5];
  const float* b0 = (const float*)d_in[6];
  const float* W1 = (const float*)d_in[7];
  const float* b1 = (const float*)d_in[8];
  const float* W2 = (const float*)d_in[9];
  const float* b2 = (const float*)d_in[10];
  const float* W3 = (const float*)d_in[11];
  const float* b3 = (const float*)d_in[12];
  const float* weight1 = (const float*)d_in[13];
  const float* bias1   = (const float*)d_in[14];

  int nfrag  = in_sizes[1];             // 1,000,000
  int ntiles = (nfrag + 15) / 16;

  unsigned short* wsW = (unsigned short*)d_ws;
  float* wg = (float*)((char*)d_ws + WG_OFF_BYTES);
  float* out = (float*)d_out;

  hipLaunchKernelGGL(init_out, dim3((out_size + 255)/256), dim3(256), 0, stream,
                     gene_ix, bias1, out, out_size);
  hipLaunchKernelGGL(prep_weights, dim3((NFRAG_TOTAL*64 + 255)/256), dim3(256), 0, stream,
                     W0, b0, W1, b1, W2, b2, W3, b3, wsW);
  hipLaunchKernelGGL(prep_wg, dim3((GENE_N*WG_STRIDE + 255)/256), dim3(256), 0, stream,
                     gene_ix, weight1, wg);
  hipLaunchKernelGGL(frag_mlp_pool, dim3(1024), dim3(64), 0, stream,
                     coords, cxg, wsW, wg, out, nfrag, ntiles);
}